// Round 1
// baseline (673.664 us; speedup 1.0000x reference)
//
#include <hip/hip_runtime.h>
#include <cstdint>

// ---- types ----
typedef __bf16  bf16;
typedef __bf16  bf16x8 __attribute__((ext_vector_type(8)));
typedef __bf16  bf16x4 __attribute__((ext_vector_type(4)));
typedef float   f32x4  __attribute__((ext_vector_type(4)));
typedef float   f32x4v __attribute__((ext_vector_type(4)));

#define GLOAD_LDS16(g, l) __builtin_amdgcn_global_load_lds( \
    (const __attribute__((address_space(1))) void*)(g),     \
    (__attribute__((address_space(3))) void*)(l), 16, 0, 0)

// dims
#define SEQ   2048
#define HID   2048
#define NH    16
#define NKV   8
#define HD    128
#define NQKV  6144   // 4096 q_all + 1024 k + 1024 v
#define MTOT  4096   // B*SEQ

// ---------------- convert x: f32 -> bf16 ----------------
__global__ __launch_bounds__(256) void convx(const float* __restrict__ x, bf16* __restrict__ xb) {
    int i = blockIdx.x * 256 + threadIdx.x;          // 4 elems / thread
    f32x4 v = ((const f32x4*)x)[i];
    bf16x4 o;
    o[0] = (bf16)v[0]; o[1] = (bf16)v[1]; o[2] = (bf16)v[2]; o[3] = (bf16)v[3];
    ((bf16x4*)xb)[i] = o;
}

// ---------------- transpose + convert weights: W (K x N) f32 -> WT (N x K=2048) bf16 ----------------
__global__ __launch_bounds__(256) void transw(const float* __restrict__ W, bf16* __restrict__ WT, int N) {
    int n0 = blockIdx.x * 64, k0 = blockIdx.y * 64;
    __shared__ float tile[64][65];
    int t = threadIdx.x;
    int tn = t & 63, t4 = t >> 6;
    #pragma unroll
    for (int i = 0; i < 16; ++i) {
        int kk = i * 4 + t4;
        tile[kk][tn] = W[(size_t)(k0 + kk) * N + n0 + tn];
    }
    __syncthreads();
    #pragma unroll
    for (int i = 0; i < 16; ++i) {
        int nn = i * 4 + t4;
        WT[(size_t)(n0 + nn) * HID + k0 + tn] = (bf16)tile[tn][nn];
    }
}

// ---------------- MFMA GEMM: C[M,N] = A[M,K] * Bt[N,K]^T ----------------
// 128x128 tile, BK=32, 256 threads (4 waves, each 64x64 quadrant), m97 structure.
template<bool OUT_BF16>
__global__ __launch_bounds__(256) void gemm_bt(const bf16* __restrict__ A, const bf16* __restrict__ Bt,
                                               void* __restrict__ C, int M, int N, int K) {
    __shared__ __align__(16) bf16 As[128 * 32];
    __shared__ __align__(16) bf16 Bs[128 * 32];
    const int tid = threadIdx.x;
    const int wave = tid >> 6, lane = tid & 63;
    const int quad = lane >> 4, cl = lane & 15;
    const int tile_n = blockIdx.x * 128, tile_m = blockIdx.y * 128;
    const int wm = (wave & 1) * 64, wn = (wave >> 1) * 64;
    f32x4 acc[4][4] = {};

    for (int k0 = 0; k0 < K; k0 += 32) {
        // stage A/B tiles: 8 KB each, 16B per lane per instr, lane-ordered LDS
        #pragma unroll
        for (int j = 0; j < 2; ++j) {
            int c = (j * 4 + wave) * 64 + lane;          // chunk 0..511
            int row = c >> 2, kq = c & 3;
            GLOAD_LDS16(A  + (size_t)(tile_m + row) * K + k0 + kq * 8, As + (size_t)(j * 4 + wave) * 512);
            GLOAD_LDS16(Bt + (size_t)(tile_n + row) * K + k0 + kq * 8, Bs + (size_t)(j * 4 + wave) * 512);
        }
        __syncthreads();
        bf16x8 a[4], b[4];
        #pragma unroll
        for (int t = 0; t < 4; ++t) {
            a[t] = *(const bf16x8*)(As + (wm + t * 16 + cl) * 32 + quad * 8);
            b[t] = *(const bf16x8*)(Bs + (wn + t * 16 + cl) * 32 + quad * 8);
        }
        #pragma unroll
        for (int mt = 0; mt < 4; ++mt)
            #pragma unroll
            for (int nt = 0; nt < 4; ++nt)
                acc[mt][nt] = __builtin_amdgcn_mfma_f32_16x16x32_bf16(a[mt], b[nt], acc[mt][nt], 0, 0, 0);
        __syncthreads();
    }
    // epilogue: C/D layout col = lane&15, row = quad*4 + r (measured m89)
    #pragma unroll
    for (int mt = 0; mt < 4; ++mt)
        #pragma unroll
        for (int nt = 0; nt < 4; ++nt)
            #pragma unroll
            for (int r = 0; r < 4; ++r) {
                int row = tile_m + wm + mt * 16 + quad * 4 + r;
                int col = tile_n + wn + nt * 16 + cl;
                float v = acc[mt][nt][r];
                if (OUT_BF16) ((bf16*)C)[(size_t)row * N + col] = (bf16)v;
                else          ((float*)C)[(size_t)row * N + col] = v;
            }
}

// ---------------- per-head RMSNorm + partial RoPE for Q and K ----------------
// one block per token; wave w handles q-heads {w,w+4,w+8,w+12} and k-heads {w,w+4}
__global__ __launch_bounds__(256) void qk_post(const bf16* __restrict__ qkv,
                                               const float* __restrict__ qnw, const float* __restrict__ knw,
                                               const int* __restrict__ positions,
                                               bf16* __restrict__ Qh, bf16* __restrict__ Kh) {
    int tk = blockIdx.x;                  // 0..4095
    int b = tk >> 11, s = tk & 2047;
    int wave = threadIdx.x >> 6, lane = threadIdx.x & 63;
    float pos = (float)positions[tk];
    // rope angle for lanes < 32 (freq idx = lane & 15); theta = 1e7: log2(theta)/16 = 1.45334354151
    int fi = lane & 15;
    float ang = pos * exp2f(-(float)fi * 1.4533435415278355f);
    float cv = cosf(ang), sv = sinf(ang);

    #pragma unroll
    for (int i = 0; i < 4; ++i) {
        int h = wave + i * 4;
        const bf16* base = qkv + (size_t)tk * NQKV + h * 256;
        float v0 = (float)base[lane], v1 = (float)base[lane + 64];
        float ssq = v0 * v0 + v1 * v1;
        #pragma unroll
        for (int off = 32; off; off >>= 1) ssq += __shfl_xor(ssq, off);
        float rn = rsqrtf(ssq * (1.0f / 128.0f) + 1e-6f);
        float q0 = v0 * rn * (1.0f + qnw[lane]);
        float q1 = v1 * rn * (1.0f + qnw[lane + 64]);
        float other = __shfl_xor(q0, 16);
        float q0r = q0;
        if (lane < 16)      q0r = q0 * cv - other * sv;
        else if (lane < 32) q0r = other * sv + q0 * cv;
        bf16* qout = Qh + ((size_t)(b * NH + h) * SEQ + s) * HD;
        qout[lane] = (bf16)q0r; qout[lane + 64] = (bf16)q1;
    }
    #pragma unroll
    for (int i = 0; i < 2; ++i) {
        int h = wave + i * 4;
        const bf16* base = qkv + (size_t)tk * NQKV + 4096 + h * HD;
        float v0 = (float)base[lane], v1 = (float)base[lane + 64];
        float ssq = v0 * v0 + v1 * v1;
        #pragma unroll
        for (int off = 32; off; off >>= 1) ssq += __shfl_xor(ssq, off);
        float rn = rsqrtf(ssq * (1.0f / 128.0f) + 1e-6f);
        float k0 = v0 * rn * (1.0f + knw[lane]);
        float k1 = v1 * rn * (1.0f + knw[lane + 64]);
        float other = __shfl_xor(k0, 16);
        float k0r = k0;
        if (lane < 16)      k0r = k0 * cv - other * sv;
        else if (lane < 32) k0r = other * sv + k0 * cv;
        bf16* kout = Kh + ((size_t)(b * NKV + h) * SEQ + s) * HD;
        kout[lane] = (bf16)k0r; kout[lane + 64] = (bf16)k1;
    }
}

// ---------------- V transpose: qkv v-slice [s][d] -> VT [b][h][d][s] ----------------
__global__ __launch_bounds__(256) void vtrans(const bf16* __restrict__ qkv, bf16* __restrict__ VT) {
    int bh = blockIdx.x >> 5;            // 0..15
    int st = blockIdx.x & 31;            // 64-token tile
    int b = bh >> 3, h = bh & 7;
    __shared__ float tile[64][129];
    int t = threadIdx.x;
    const bf16* src = qkv + ((size_t)(b * SEQ) + st * 64) * NQKV + 5120 + h * HD;
    #pragma unroll
    for (int i = 0; i < 32; ++i) {
        int idx = i * 256 + t;
        int tok = idx >> 7, d = idx & 127;
        tile[tok][d] = (float)src[(size_t)tok * NQKV + d];
    }
    __syncthreads();
    bf16* dst = VT + (size_t)(b * NKV + h) * HD * SEQ + st * 64;
    #pragma unroll
    for (int i = 0; i < 32; ++i) {
        int idx = i * 256 + t;
        int d = idx >> 6, sx = idx & 63;
        dst[(size_t)d * SEQ + sx] = (bf16)tile[sx][d];
    }
}

// ---------------- flash attention, Br=Bc=64, 4 waves x 16 q-rows, fused sigmoid gate ----------------
__global__ __launch_bounds__(256) void attn_kernel(const bf16* __restrict__ Qh, const bf16* __restrict__ Kh,
                                                   const bf16* __restrict__ VT, const bf16* __restrict__ qkv,
                                                   const int* __restrict__ amask, bf16* __restrict__ attnb) {
    const int qt = blockIdx.x & 31, head = (blockIdx.x >> 5) & 15, b = blockIdx.x >> 9;
    const int kvh = head >> 1;
    __shared__ __align__(16) bf16 Qs[64 * 128];
    __shared__ __align__(16) bf16 Ks[64 * 128];
    __shared__ __align__(16) bf16 Vs[128 * 64];   // [d][s]
    __shared__ __align__(16) bf16 Ps[4 * 16 * 64];
    const int tid = threadIdx.x, wave = tid >> 6, lane = tid & 63;
    const int quad = lane >> 4, cl = lane & 15;

    // stage Q tile once (64x128 bf16 = 1024 x 16B chunks)
    const bf16* qsrc = Qh + ((size_t)(b * NH + head) * SEQ + qt * 64) * HD;
    #pragma unroll
    for (int j = 0; j < 4; ++j) {
        int c = (j * 4 + wave) * 64 + lane;
        GLOAD_LDS16(qsrc + (size_t)c * 8, Qs + (size_t)(j * 4 + wave) * 512);
    }

    float mstate[4], lstate[4];
    f32x4 oacc[8] = {};
    #pragma unroll
    for (int r = 0; r < 4; ++r) { mstate[r] = -1e30f; lstate[r] = 0.0f; }
    const int qrow_glob = qt * 64 + wave * 16 + quad * 4;   // + r
    const float scale = 0.08838834764831845f;               // 1/sqrt(128)

    for (int kt = 0; kt <= qt; ++kt) {
        __syncthreads();   // protect Ks/Vs reuse (also drains Q staging on iter 0)
        const bf16* ksrc = Kh + ((size_t)(b * NKV + kvh) * SEQ + kt * 64) * HD;
        const bf16* vsrc = VT + (size_t)(b * NKV + kvh) * HD * SEQ + kt * 64;
        #pragma unroll
        for (int j = 0; j < 4; ++j) {
            int c = (j * 4 + wave) * 64 + lane;
            GLOAD_LDS16(ksrc + (size_t)c * 8, Ks + (size_t)(j * 4 + wave) * 512);
            int d = c >> 3, part = c & 7;
            GLOAD_LDS16(vsrc + (size_t)d * SEQ + part * 8, Vs + (size_t)(j * 4 + wave) * 512);
        }
        __syncthreads();

        // S = Q K^T  (16 rows x 64 cols per wave)
        bf16x8 aq[4];
        #pragma unroll
        for (int kc = 0; kc < 4; ++kc)
            aq[kc] = *(const bf16x8*)(Qs + (wave * 16 + cl) * 128 + kc * 32 + quad * 8);
        f32x4 sc[4] = {};
        #pragma unroll
        for (int nt = 0; nt < 4; ++nt)
            #pragma unroll
            for (int kc = 0; kc < 4; ++kc) {
                bf16x8 bk = *(const bf16x8*)(Ks + (nt * 16 + cl) * 128 + kc * 32 + quad * 8);
                sc[nt] = __builtin_amdgcn_mfma_f32_16x16x32_bf16(aq[kc], bk, sc[nt], 0, 0, 0);
            }

        // mask per column (same for all r)
        bool colok[4];
        int kcolb[4];
        #pragma unroll
        for (int nt = 0; nt < 4; ++nt) {
            kcolb[nt] = kt * 64 + nt * 16 + cl;
            colok[nt] = (amask[b * SEQ + kcolb[nt]] != 0);
        }

        float alpha[4];
        #pragma unroll
        for (int r = 0; r < 4; ++r) {
            float rv[4];
            float tmax = -1e30f;
            #pragma unroll
            for (int nt = 0; nt < 4; ++nt) {
                float v = sc[nt][r] * scale;
                bool ok = colok[nt] && (kcolb[nt] <= qrow_glob + r);
                v = ok ? v : -1e30f;
                rv[nt] = v;
                tmax = fmaxf(tmax, v);
            }
            #pragma unroll
            for (int off = 8; off; off >>= 1) tmax = fmaxf(tmax, __shfl_xor(tmax, off));
            float mnew = fmaxf(mstate[r], tmax);
            float al = __expf(mstate[r] - mnew);
            mstate[r] = mnew; alpha[r] = al;
            float rsum = 0.0f;
            #pragma unroll
            for (int nt = 0; nt < 4; ++nt) {
                float p = __expf(rv[nt] - mnew);
                rsum += p;
                Ps[wave * 1024 + (quad * 4 + r) * 64 + nt * 16 + cl] = (bf16)p;
            }
            #pragma unroll
            for (int off = 8; off; off >>= 1) rsum += __shfl_xor(rsum, off);
            lstate[r] = lstate[r] * al + rsum;
        }
        #pragma unroll
        for (int n2 = 0; n2 < 8; ++n2)
            #pragma unroll
            for (int r = 0; r < 4; ++r) oacc[n2][r] *= alpha[r];

        // O += P V   (P: A-layout from per-wave LDS; V^T: B-operand, 8 consecutive seq)
        bf16x8 ap[2];
        #pragma unroll
        for (int c = 0; c < 2; ++c)
            ap[c] = *(const bf16x8*)(Ps + wave * 1024 + cl * 64 + c * 32 + quad * 8);
        #pragma unroll
        for (int n2 = 0; n2 < 8; ++n2)
            #pragma unroll
            for (int c = 0; c < 2; ++c) {
                bf16x8 bv = *(const bf16x8*)(Vs + (n2 * 16 + cl) * 64 + c * 32 + quad * 8);
                oacc[n2] = __builtin_amdgcn_mfma_f32_16x16x32_bf16(ap[c], bv, oacc[n2], 0, 0, 0);
            }
    }

    // epilogue: O/l, apply sigmoid gate, write bf16 [b][s][h*128+d]
    #pragma unroll
    for (int r = 0; r < 4; ++r) {
        int srow = qrow_glob + r;
        float linv = 1.0f / lstate[r];
        #pragma unroll
        for (int n2 = 0; n2 < 8; ++n2) {
            int d = n2 * 16 + cl;
            float g = (float)qkv[(size_t)(b * SEQ + srow) * NQKV + head * 256 + 128 + d];
            float sig = 1.0f / (1.0f + __expf(-g));
            float v = oacc[n2][r] * linv * sig;
            attnb[(size_t)(b * SEQ + srow) * HID + head * HD + d] = (bf16)v;
        }
    }
}

// ---------------- launch ----------------
extern "C" void kernel_launch(void* const* d_in, const int* in_sizes, int n_in,
                              void* d_out, int out_size, void* d_ws, size_t ws_size,
                              hipStream_t stream) {
    const float* x        = (const float*)d_in[0];
    const int*   amask    = (const int*)d_in[1];
    const int*   positions= (const int*)d_in[2];
    const float* Wq       = (const float*)d_in[3];
    const float* Wk       = (const float*)d_in[4];
    const float* Wv       = (const float*)d_in[5];
    const float* Wo       = (const float*)d_in[6];
    const float* qnw      = (const float*)d_in[7];
    const float* knw      = (const float*)d_in[8];
    float* out = (float*)d_out;
    char* ws = (char*)d_ws;

    bf16* xb    = (bf16*)(ws);                         // 4096x2048        16,777,216 B
    bf16* wqkvT = (bf16*)(ws + 16777216);              // 6144x2048        25,165,824 B
    bf16* woT   = (bf16*)(ws + 41943040);              // 2048x2048         8,388,608 B
    bf16* qkv   = (bf16*)(ws + 50331648);              // 4096x6144        50,331,648 B
    bf16* Qh    = (bf16*)(ws + 100663296);             // 16h x 2048 x 128 16,777,216 B
    bf16* Kh    = (bf16*)(ws + 117440512);             //  8h x 2048 x 128  8,388,608 B
    bf16* VT    = (bf16*)(ws + 125829120);             //  8h x 128 x 2048  8,388,608 B
    bf16* attnb = (bf16*)(ws + 134217728);             // 4096x2048        16,777,216 B -> 150,994,944 total

    convx<<<8192, 256, 0, stream>>>(x, xb);
    transw<<<dim3(64, 32), 256, 0, stream>>>(Wq, wqkvT, 4096);
    transw<<<dim3(16, 32), 256, 0, stream>>>(Wk, wqkvT + (size_t)4096 * HID, 1024);
    transw<<<dim3(16, 32), 256, 0, stream>>>(Wv, wqkvT + (size_t)5120 * HID, 1024);
    transw<<<dim3(32, 32), 256, 0, stream>>>(Wo, woT, 2048);

    gemm_bt<true><<<dim3(48, 32), 256, 0, stream>>>(xb, wqkvT, qkv, MTOT, NQKV, HID);
    qk_post<<<4096, 256, 0, stream>>>(qkv, qnw, knw, positions, Qh, Kh);
    vtrans<<<512, 256, 0, stream>>>(qkv, VT);
    attn_kernel<<<1024, 256, 0, stream>>>(Qh, Kh, VT, qkv, amask, attnb);
    gemm_bt<false><<<dim3(16, 32), 256, 0, stream>>>(attnb, woT, out, MTOT, HID, HID);

    (void)in_sizes; (void)n_in; (void)out_size; (void)ws_size;
}

// Round 3
// 484.456 us; speedup vs baseline: 1.3906x; 1.3906x over previous
//
#include <hip/hip_runtime.h>
#include <cstdint>

// ---- types ----
typedef __bf16  bf16;
typedef __bf16  bf16x8 __attribute__((ext_vector_type(8)));
typedef __bf16  bf16x4 __attribute__((ext_vector_type(4)));
typedef float   f32x4  __attribute__((ext_vector_type(4)));

#define GLOAD_LDS16(g, l) __builtin_amdgcn_global_load_lds( \
    (const __attribute__((address_space(1))) void*)(g),     \
    (__attribute__((address_space(3))) void*)(l), 16, 0, 0)

// dims
#define SEQ   2048
#define HID   2048
#define NH    16
#define NKV   8
#define HD    128
#define NQKV  6144   // 4096 q_all + 1024 k + 1024 v
#define MTOT  4096   // B*SEQ

// ---------------- convert x: f32 -> bf16 ----------------
__global__ __launch_bounds__(256) void convx(const float* __restrict__ x, bf16* __restrict__ xb) {
    int i = blockIdx.x * 256 + threadIdx.x;          // 4 elems / thread
    f32x4 v = ((const f32x4*)x)[i];
    bf16x4 o;
    o[0] = (bf16)v[0]; o[1] = (bf16)v[1]; o[2] = (bf16)v[2]; o[3] = (bf16)v[3];
    ((bf16x4*)xb)[i] = o;
}

// ---------------- transpose + convert weights: W (K x N) f32 -> WT (N x K=2048) bf16 ----------------
__global__ __launch_bounds__(256) void transw(const float* __restrict__ W, bf16* __restrict__ WT, int N) {
    int n0 = blockIdx.x * 64, k0 = blockIdx.y * 64;
    __shared__ float tile[64][65];
    int t = threadIdx.x;
    int tn = t & 63, t4 = t >> 6;
    #pragma unroll
    for (int i = 0; i < 16; ++i) {
        int kk = i * 4 + t4;
        tile[kk][tn] = W[(size_t)(k0 + kk) * N + n0 + tn];
    }
    __syncthreads();
    #pragma unroll
    for (int i = 0; i < 16; ++i) {
        int nn = i * 4 + t4;
        WT[(size_t)(n0 + nn) * HID + k0 + tn] = (bf16)tile[tn][nn];
    }
}

// ---------------- MFMA GEMM: C[M,N] = A[M,K] * Bt[N,K]^T ----------------
// 128x128 tile, BK=32, 256 threads (4 waves, each 64x64 quadrant), m97 structure.
template<bool OUT_BF16>
__global__ __launch_bounds__(256) void gemm_bt(const bf16* __restrict__ A, const bf16* __restrict__ Bt,
                                               void* __restrict__ C, int M, int N, int K) {
    __shared__ __align__(16) bf16 As[128 * 32];
    __shared__ __align__(16) bf16 Bs[128 * 32];
    const int tid = threadIdx.x;
    const int wave = tid >> 6, lane = tid & 63;
    const int quad = lane >> 4, cl = lane & 15;
    const int tile_n = blockIdx.x * 128, tile_m = blockIdx.y * 128;
    const int wm = (wave & 1) * 64, wn = (wave >> 1) * 64;
    f32x4 acc[4][4] = {};

    for (int k0 = 0; k0 < K; k0 += 32) {
        #pragma unroll
        for (int j = 0; j < 2; ++j) {
            int c = (j * 4 + wave) * 64 + lane;          // chunk 0..511
            int row = c >> 2, kq = c & 3;
            GLOAD_LDS16(A  + (size_t)(tile_m + row) * K + k0 + kq * 8, As + (size_t)(j * 4 + wave) * 512);
            GLOAD_LDS16(Bt + (size_t)(tile_n + row) * K + k0 + kq * 8, Bs + (size_t)(j * 4 + wave) * 512);
        }
        __syncthreads();
        bf16x8 a[4], b[4];
        #pragma unroll
        for (int t = 0; t < 4; ++t) {
            a[t] = *(const bf16x8*)(As + (wm + t * 16 + cl) * 32 + quad * 8);
            b[t] = *(const bf16x8*)(Bs + (wn + t * 16 + cl) * 32 + quad * 8);
        }
        #pragma unroll
        for (int mt = 0; mt < 4; ++mt)
            #pragma unroll
            for (int nt = 0; nt < 4; ++nt)
                acc[mt][nt] = __builtin_amdgcn_mfma_f32_16x16x32_bf16(a[mt], b[nt], acc[mt][nt], 0, 0, 0);
        __syncthreads();
    }
    #pragma unroll
    for (int mt = 0; mt < 4; ++mt)
        #pragma unroll
        for (int nt = 0; nt < 4; ++nt)
            #pragma unroll
            for (int r = 0; r < 4; ++r) {
                int row = tile_m + wm + mt * 16 + quad * 4 + r;
                int col = tile_n + wn + nt * 16 + cl;
                float v = acc[mt][nt][r];
                if (OUT_BF16) ((bf16*)C)[(size_t)row * N + col] = (bf16)v;
                else          ((float*)C)[(size_t)row * N + col] = v;
            }
}

// ---------------- per-head RMSNorm + partial RoPE for Q and K ----------------
__global__ __launch_bounds__(256) void qk_post(const bf16* __restrict__ qkv,
                                               const float* __restrict__ qnw, const float* __restrict__ knw,
                                               const int* __restrict__ positions,
                                               bf16* __restrict__ Qh, bf16* __restrict__ Kh) {
    int tk = blockIdx.x;                  // 0..4095
    int b = tk >> 11, s = tk & 2047;
    int wave = threadIdx.x >> 6, lane = threadIdx.x & 63;
    float pos = (float)positions[tk];
    int fi = lane & 15;
    float ang = pos * exp2f(-(float)fi * 1.4533435415278355f);
    float cv = cosf(ang), sv = sinf(ang);

    #pragma unroll
    for (int i = 0; i < 4; ++i) {
        int h = wave + i * 4;
        const bf16* base = qkv + (size_t)tk * NQKV + h * 256;
        float v0 = (float)base[lane], v1 = (float)base[lane + 64];
        float ssq = v0 * v0 + v1 * v1;
        #pragma unroll
        for (int off = 32; off; off >>= 1) ssq += __shfl_xor(ssq, off);
        float rn = rsqrtf(ssq * (1.0f / 128.0f) + 1e-6f);
        float q0 = v0 * rn * (1.0f + qnw[lane]);
        float q1 = v1 * rn * (1.0f + qnw[lane + 64]);
        float other = __shfl_xor(q0, 16);
        float q0r = q0;
        if (lane < 16)      q0r = q0 * cv - other * sv;
        else if (lane < 32) q0r = other * sv + q0 * cv;
        bf16* qout = Qh + ((size_t)(b * NH + h) * SEQ + s) * HD;
        qout[lane] = (bf16)q0r; qout[lane + 64] = (bf16)q1;
    }
    #pragma unroll
    for (int i = 0; i < 2; ++i) {
        int h = wave + i * 4;
        const bf16* base = qkv + (size_t)tk * NQKV + 4096 + h * HD;
        float v0 = (float)base[lane], v1 = (float)base[lane + 64];
        float ssq = v0 * v0 + v1 * v1;
        #pragma unroll
        for (int off = 32; off; off >>= 1) ssq += __shfl_xor(ssq, off);
        float rn = rsqrtf(ssq * (1.0f / 128.0f) + 1e-6f);
        float k0 = v0 * rn * (1.0f + knw[lane]);
        float k1 = v1 * rn * (1.0f + knw[lane + 64]);
        float other = __shfl_xor(k0, 16);
        float k0r = k0;
        if (lane < 16)      k0r = k0 * cv - other * sv;
        else if (lane < 32) k0r = other * sv + k0 * cv;
        bf16* kout = Kh + ((size_t)(b * NKV + h) * SEQ + s) * HD;
        kout[lane] = (bf16)k0r; kout[lane + 64] = (bf16)k1;
    }
}

// ---------------- V transpose: qkv v-slice [s][d] -> VT [b][h][d][s] ----------------
__global__ __launch_bounds__(256) void vtrans(const bf16* __restrict__ qkv, bf16* __restrict__ VT) {
    int bh = blockIdx.x >> 5;            // 0..15
    int st = blockIdx.x & 31;            // 64-token tile
    int b = bh >> 3, h = bh & 7;
    __shared__ float tile[64][129];
    int t = threadIdx.x;
    const bf16* src = qkv + ((size_t)(b * SEQ) + st * 64) * NQKV + 5120 + h * HD;
    #pragma unroll
    for (int i = 0; i < 32; ++i) {
        int idx = i * 256 + t;
        int tok = idx >> 7, d = idx & 127;
        tile[tok][d] = (float)src[(size_t)tok * NQKV + d];
    }
    __syncthreads();
    bf16* dst = VT + (size_t)(b * NKV + h) * HD * SEQ + st * 64;
    #pragma unroll
    for (int i = 0; i < 32; ++i) {
        int idx = i * 256 + t;
        int d = idx >> 6, sx = idx & 63;
        dst[(size_t)d * SEQ + sx] = (bf16)tile[sx][d];
    }
}

// ---------------- flash attention, Br=Bc=64, 4 waves x 16 q-rows ----------------
// Q in registers; K/V/P in XOR-swizzled LDS (conflict-free); qt remapped for
// causal load balance across co-resident blocks.
__global__ __launch_bounds__(256, 4) void attn_kernel(const bf16* __restrict__ Qh, const bf16* __restrict__ Kh,
                                                      const bf16* __restrict__ VT, const bf16* __restrict__ qkv,
                                                      const int* __restrict__ amask, bf16* __restrict__ attnb) {
    const int bx = blockIdx.x;
    const int hb = bx >> 5;                 // 0..31
    const int head = hb & 15, b = hb >> 4;
    const int qt = ((bx & 31) + hb) & 31;   // stride-256 co-resident blocks get qt +{0,8,16,24}
    const int kvh = head >> 1;
    __shared__ __align__(16) bf16 Ks[64 * 128];   // [row][chunk ^ (row&15)] (16B chunks)
    __shared__ __align__(16) bf16 Vs[128 * 64];   // [d][chunk ^ (d&7)]
    __shared__ __align__(16) bf16 Ps[4 * 16 * 64];// per-wave, col ^ ((row>>2)*16)
    const int tid = threadIdx.x, wave = tid >> 6, lane = tid & 63;
    const int quad = lane >> 4, cl = lane & 15;

    // Q fragments in registers (loop-invariant). A[m][k]: m=cl, k=quad*8+j.
    const bf16* qsrc = Qh + ((size_t)(b * NH + head) * SEQ + qt * 64) * HD;
    bf16x8 aq[4];
    #pragma unroll
    for (int kc = 0; kc < 4; ++kc)
        aq[kc] = *(const bf16x8*)(qsrc + (size_t)(wave * 16 + cl) * HD + kc * 32 + quad * 8);

    float mstate[4], lstate[4];
    f32x4 oacc[8] = {};
    #pragma unroll
    for (int r = 0; r < 4; ++r) { mstate[r] = -1e30f; lstate[r] = 0.0f; }
    const int qrow_glob = qt * 64 + wave * 16 + quad * 4;   // + r
    const float scale = 0.08838834764831845f;               // 1/sqrt(128)

    for (int kt = 0; kt <= qt; ++kt) {
        __syncthreads();   // all waves done reading prev K/V
        const bf16* ksrc = Kh + ((size_t)(b * NKV + kvh) * SEQ + kt * 64) * HD;
        const bf16* vsrc = VT + (size_t)(b * NKV + kvh) * HD * SEQ + kt * 64;
        #pragma unroll
        for (int j = 0; j < 4; ++j) {
            int s = (j * 4 + wave) * 64 + lane;       // 16B-chunk slot 0..1023
            int rK = s >> 4, cK = s & 15;             // K: 64 rows x 16 chunks
            GLOAD_LDS16(ksrc + (size_t)rK * HD + ((cK ^ (rK & 15)) << 3), Ks + (size_t)s * 8);
            int dV = s >> 3, cV = s & 7;              // V: 128 rows x 8 chunks
            GLOAD_LDS16(vsrc + (size_t)dV * SEQ + ((cV ^ (dV & 7)) << 3), Vs + (size_t)s * 8);
        }
        __syncthreads();

        // S = Q K^T  (16 rows x 64 cols per wave); Ks chunk swizzle: ^ (row&15)=cl
        f32x4 sc[4] = {};
        #pragma unroll
        for (int nt = 0; nt < 4; ++nt)
            #pragma unroll
            for (int kc = 0; kc < 4; ++kc) {
                bf16x8 bk = *(const bf16x8*)(Ks + (size_t)(nt * 16 + cl) * 128 + (((kc * 4 + quad) ^ cl) << 3));
                sc[nt] = __builtin_amdgcn_mfma_f32_16x16x32_bf16(aq[kc], bk, sc[nt], 0, 0, 0);
            }

        bool colok[4];
        int kcolb[4];
        #pragma unroll
        for (int nt = 0; nt < 4; ++nt) {
            kcolb[nt] = kt * 64 + nt * 16 + cl;
            colok[nt] = (amask[b * SEQ + kcolb[nt]] != 0);
        }

        float alpha[4];
        #pragma unroll
        for (int r = 0; r < 4; ++r) {
            float rv[4];
            float tmax = -1e30f;
            #pragma unroll
            for (int nt = 0; nt < 4; ++nt) {
                float v = sc[nt][r] * scale;
                bool ok = colok[nt] && (kcolb[nt] <= qrow_glob + r);
                v = ok ? v : -1e30f;
                rv[nt] = v;
                tmax = fmaxf(tmax, v);
            }
            #pragma unroll
            for (int off = 8; off; off >>= 1) tmax = fmaxf(tmax, __shfl_xor(tmax, off));
            float mnew = fmaxf(mstate[r], tmax);
            float al = __expf(mstate[r] - mnew);
            mstate[r] = mnew; alpha[r] = al;
            float rsum = 0.0f;
            int prow = quad * 4 + r;
            #pragma unroll
            for (int nt = 0; nt < 4; ++nt) {
                float p = __expf(rv[nt] - mnew);
                rsum += p;
                Ps[wave * 1024 + prow * 64 + ((nt * 16 + cl) ^ (quad << 4))] = (bf16)p;
            }
            #pragma unroll
            for (int off = 8; off; off >>= 1) rsum += __shfl_xor(rsum, off);
            lstate[r] = lstate[r] * al + rsum;
        }
        #pragma unroll
        for (int n2 = 0; n2 < 8; ++n2)
            #pragma unroll
            for (int r = 0; r < 4; ++r) oacc[n2][r] *= alpha[r];

        // O += P V   (P A-frag: row=cl, cols quad*8+c*32; swizzle ^ ((cl>>2)*16))
        bf16x8 ap[2];
        #pragma unroll
        for (int c = 0; c < 2; ++c)
            ap[c] = *(const bf16x8*)(Ps + wave * 1024 + cl * 64 + ((c * 32 + quad * 8) ^ ((cl >> 2) << 4)));
        #pragma unroll
        for (int n2 = 0; n2 < 8; ++n2)
            #pragma unroll
            for (int c = 0; c < 2; ++c) {
                bf16x8 bv = *(const bf16x8*)(Vs + (size_t)(n2 * 16 + cl) * 64 + (((c * 4 + quad) ^ (cl & 7)) << 3));
                oacc[n2] = __builtin_amdgcn_mfma_f32_16x16x32_bf16(ap[c], bv, oacc[n2], 0, 0, 0);
            }
    }

    // epilogue: O/l, sigmoid gate, write bf16 [b][s][h*128+d]
    #pragma unroll
    for (int r = 0; r < 4; ++r) {
        int srow = qt * 64 + wave * 16 + quad * 4 + r;
        float linv = 1.0f / lstate[r];
        #pragma unroll
        for (int n2 = 0; n2 < 8; ++n2) {
            int d = n2 * 16 + cl;
            float g = (float)qkv[(size_t)(b * SEQ + srow) * NQKV + head * 256 + 128 + d];
            float sig = 1.0f / (1.0f + __expf(-g));
            float v = oacc[n2][r] * linv * sig;
            attnb[(size_t)(b * SEQ + srow) * HID + head * HD + d] = (bf16)v;
        }
    }
}

// ---------------- launch ----------------
extern "C" void kernel_launch(void* const* d_in, const int* in_sizes, int n_in,
                              void* d_out, int out_size, void* d_ws, size_t ws_size,
                              hipStream_t stream) {
    const float* x        = (const float*)d_in[0];
    const int*   amask    = (const int*)d_in[1];
    const int*   positions= (const int*)d_in[2];
    const float* Wq       = (const float*)d_in[3];
    const float* Wk       = (const float*)d_in[4];
    const float* Wv       = (const float*)d_in[5];
    const float* Wo       = (const float*)d_in[6];
    const float* qnw      = (const float*)d_in[7];
    const float* knw      = (const float*)d_in[8];
    float* out = (float*)d_out;
    char* ws = (char*)d_ws;

    bf16* xb    = (bf16*)(ws);                         // 4096x2048        16,777,216 B
    bf16* wqkvT = (bf16*)(ws + 16777216);              // 6144x2048        25,165,824 B
    bf16* woT   = (bf16*)(ws + 41943040);              // 2048x2048         8,388,608 B
    bf16* qkv   = (bf16*)(ws + 50331648);              // 4096x6144        50,331,648 B
    bf16* Qh    = (bf16*)(ws + 100663296);             // 16h x 2048 x 128 16,777,216 B
    bf16* Kh    = (bf16*)(ws + 117440512);             //  8h x 2048 x 128  8,388,608 B
    bf16* VT    = (bf16*)(ws + 125829120);             //  8h x 128 x 2048  8,388,608 B
    bf16* attnb = (bf16*)(ws + 134217728);             // 4096x2048        16,777,216 B -> 150,994,944 total

    convx<<<8192, 256, 0, stream>>>(x, xb);
    transw<<<dim3(64, 32), 256, 0, stream>>>(Wq, wqkvT, 4096);
    transw<<<dim3(16, 32), 256, 0, stream>>>(Wk, wqkvT + (size_t)4096 * HID, 1024);
    transw<<<dim3(16, 32), 256, 0, stream>>>(Wv, wqkvT + (size_t)5120 * HID, 1024);
    transw<<<dim3(32, 32), 256, 0, stream>>>(Wo, woT, 2048);

    gemm_bt<true><<<dim3(48, 32), 256, 0, stream>>>(xb, wqkvT, qkv, MTOT, NQKV, HID);
    qk_post<<<4096, 256, 0, stream>>>(qkv, qnw, knw, positions, Qh, Kh);
    vtrans<<<512, 256, 0, stream>>>(qkv, VT);
    attn_kernel<<<1024, 256, 0, stream>>>(Qh, Kh, VT, qkv, amask, attnb);
    gemm_bt<false><<<dim3(16, 32), 256, 0, stream>>>(attnb, woT, out, MTOT, HID, HID);

    (void)in_sizes; (void)n_in; (void)out_size; (void)ws_size;
}

// Round 4
// 481.393 us; speedup vs baseline: 1.3994x; 1.0064x over previous
//
#include <hip/hip_runtime.h>
#include <cstdint>

// ---- types ----
typedef __bf16  bf16;
typedef __bf16  bf16x8 __attribute__((ext_vector_type(8)));
typedef __bf16  bf16x4 __attribute__((ext_vector_type(4)));
typedef float   f32x4  __attribute__((ext_vector_type(4)));
typedef float   f32x16 __attribute__((ext_vector_type(16)));

#define GLOAD_LDS16(g, l) __builtin_amdgcn_global_load_lds( \
    (const __attribute__((address_space(1))) void*)(g),     \
    (__attribute__((address_space(3))) void*)(l), 16, 0, 0)

// dims
#define SEQ   2048
#define HID   2048
#define NH    16
#define NKV   8
#define HD    128
#define NQKV  6144   // 4096 q_all + 1024 k + 1024 v
#define MTOT  4096   // B*SEQ

// ---------------- fused prep: convx + all weight transposes ----------------
__device__ __forceinline__ void transw_body(const float* __restrict__ W, bf16* __restrict__ WT,
                                            int N, int n0, int k0, int t) {
    __shared__ float tile[64][65];
    int tn = t & 63, t4 = t >> 6;
    #pragma unroll
    for (int i = 0; i < 16; ++i) {
        int kk = i * 4 + t4;
        tile[kk][tn] = W[(size_t)(k0 + kk) * N + n0 + tn];
    }
    __syncthreads();
    #pragma unroll
    for (int i = 0; i < 16; ++i) {
        int nn = i * 4 + t4;
        WT[(size_t)(n0 + nn) * HID + k0 + tn] = (bf16)tile[tn][nn];
    }
}

__global__ __launch_bounds__(256) void prep_kernel(const float* __restrict__ x, bf16* __restrict__ xb,
                                                   const float* __restrict__ Wq, const float* __restrict__ Wk,
                                                   const float* __restrict__ Wv, const float* __restrict__ Wo,
                                                   bf16* __restrict__ wqkvT, bf16* __restrict__ woT) {
    int bx = blockIdx.x, t = threadIdx.x;
    if (bx < 8192) {                                   // convx: 4 f32->bf16 per thread
        int i = bx * 256 + t;
        f32x4 v = ((const f32x4*)x)[i];
        bf16x4 o;
        o[0] = (bf16)v[0]; o[1] = (bf16)v[1]; o[2] = (bf16)v[2]; o[3] = (bf16)v[3];
        ((bf16x4*)xb)[i] = o;
    } else if (bx < 8192 + 2048) {                     // Wq: N=4096, 64x32 tiles
        int idx = bx - 8192;
        transw_body(Wq, wqkvT, 4096, (idx & 63) * 64, (idx >> 6) * 64, t);
    } else if (bx < 8192 + 2048 + 512) {               // Wk: N=1024
        int idx = bx - (8192 + 2048);
        transw_body(Wk, wqkvT + (size_t)4096 * HID, 1024, (idx & 15) * 64, (idx >> 4) * 64, t);
    } else if (bx < 8192 + 2048 + 1024) {              // Wv: N=1024
        int idx = bx - (8192 + 2048 + 512);
        transw_body(Wv, wqkvT + (size_t)5120 * HID, 1024, (idx & 15) * 64, (idx >> 4) * 64, t);
    } else {                                           // Wo: N=2048
        int idx = bx - (8192 + 2048 + 1024);
        transw_body(Wo, woT, 2048, (idx & 31) * 64, (idx >> 5) * 64, t);
    }
}

// ---------------- MFMA GEMM: C[M,N] = A[M,K] * Bt[N,K]^T ----------------
// 128x128 tile, BK=32, 256 threads (4 waves, 64x64 quadrants), 32x32x16 MFMA.
template<bool OUT_BF16>
__global__ __launch_bounds__(256) void gemm_bt(const bf16* __restrict__ A, const bf16* __restrict__ Bt,
                                               void* __restrict__ C, int M, int N, int K) {
    __shared__ __align__(16) bf16 As[128 * 32];
    __shared__ __align__(16) bf16 Bs[128 * 32];
    const int tid = threadIdx.x;
    const int wave = tid >> 6, lane = tid & 63;
    const int l31 = lane & 31, half = lane >> 5;
    const int tile_n = blockIdx.x * 128, tile_m = blockIdx.y * 128;
    const int wm = (wave & 1) * 64, wn = (wave >> 1) * 64;
    f32x16 acc[2][2] = {};

    for (int k0 = 0; k0 < K; k0 += 32) {
        #pragma unroll
        for (int j = 0; j < 2; ++j) {
            int c = (j * 4 + wave) * 64 + lane;          // chunk 0..511
            int row = c >> 2, kq = c & 3;
            GLOAD_LDS16(A  + (size_t)(tile_m + row) * K + k0 + kq * 8, As + (size_t)(j * 4 + wave) * 512);
            GLOAD_LDS16(Bt + (size_t)(tile_n + row) * K + k0 + kq * 8, Bs + (size_t)(j * 4 + wave) * 512);
        }
        __syncthreads();
        // A frag: m = l31 (row), k = half*8 + j within kh*16 half
        bf16x8 a[2][2], b[2][2];
        #pragma unroll
        for (int mt = 0; mt < 2; ++mt)
            #pragma unroll
            for (int kh = 0; kh < 2; ++kh) {
                a[mt][kh] = *(const bf16x8*)(As + (size_t)(wm + mt * 32 + l31) * 32 + kh * 16 + half * 8);
                b[mt][kh] = *(const bf16x8*)(Bs + (size_t)(wn + mt * 32 + l31) * 32 + kh * 16 + half * 8);
            }
        #pragma unroll
        for (int mt = 0; mt < 2; ++mt)
            #pragma unroll
            for (int nt = 0; nt < 2; ++nt)
                #pragma unroll
                for (int kh = 0; kh < 2; ++kh)
                    acc[mt][nt] = __builtin_amdgcn_mfma_f32_32x32x16_bf16(a[mt][kh], b[nt][kh], acc[mt][nt], 0, 0, 0);
        __syncthreads();
    }
    // epilogue: C/D layout (m74/m101): col = lane&31, row = (reg&3) + 8*(reg>>2) + 4*(lane>>5)
    #pragma unroll
    for (int mt = 0; mt < 2; ++mt)
        #pragma unroll
        for (int nt = 0; nt < 2; ++nt)
            #pragma unroll
            for (int reg = 0; reg < 16; ++reg) {
                int row = tile_m + wm + mt * 32 + (reg & 3) + ((reg >> 2) * 8) + half * 4;
                int col = tile_n + wn + nt * 32 + l31;
                float v = acc[mt][nt][reg];
                if (OUT_BF16) ((bf16*)C)[(size_t)row * N + col] = (bf16)v;
                else          ((float*)C)[(size_t)row * N + col] = v;
            }
}

// ---------------- fused post: per-head RMSNorm+RoPE (Q,K) + V transpose ----------------
__global__ __launch_bounds__(256) void post_kernel(const bf16* __restrict__ qkv,
                                                   const float* __restrict__ qnw, const float* __restrict__ knw,
                                                   const int* __restrict__ positions,
                                                   bf16* __restrict__ Qh, bf16* __restrict__ Kh,
                                                   bf16* __restrict__ VT) {
    int bx = blockIdx.x;
    if (bx < 4096) {
        int tk = bx;                      // token 0..4095
        int b = tk >> 11, s = tk & 2047;
        int wave = threadIdx.x >> 6, lane = threadIdx.x & 63;
        float pos = (float)positions[tk];
        int fi = lane & 15;
        float ang = pos * exp2f(-(float)fi * 1.4533435415278355f);
        float cv = cosf(ang), sv = sinf(ang);

        #pragma unroll
        for (int i = 0; i < 4; ++i) {
            int h = wave + i * 4;
            const bf16* base = qkv + (size_t)tk * NQKV + h * 256;
            float v0 = (float)base[lane], v1 = (float)base[lane + 64];
            float ssq = v0 * v0 + v1 * v1;
            #pragma unroll
            for (int off = 32; off; off >>= 1) ssq += __shfl_xor(ssq, off);
            float rn = rsqrtf(ssq * (1.0f / 128.0f) + 1e-6f);
            float q0 = v0 * rn * (1.0f + qnw[lane]);
            float q1 = v1 * rn * (1.0f + qnw[lane + 64]);
            float other = __shfl_xor(q0, 16);
            float q0r = q0;
            if (lane < 16)      q0r = q0 * cv - other * sv;
            else if (lane < 32) q0r = other * sv + q0 * cv;
            bf16* qout = Qh + ((size_t)(b * NH + h) * SEQ + s) * HD;
            qout[lane] = (bf16)q0r; qout[lane + 64] = (bf16)q1;
        }
        #pragma unroll
        for (int i = 0; i < 2; ++i) {
            int h = wave + i * 4;
            const bf16* base = qkv + (size_t)tk * NQKV + 4096 + h * HD;
            float v0 = (float)base[lane], v1 = (float)base[lane + 64];
            float ssq = v0 * v0 + v1 * v1;
            #pragma unroll
            for (int off = 32; off; off >>= 1) ssq += __shfl_xor(ssq, off);
            float rn = rsqrtf(ssq * (1.0f / 128.0f) + 1e-6f);
            float k0 = v0 * rn * (1.0f + knw[lane]);
            float k1 = v1 * rn * (1.0f + knw[lane + 64]);
            float other = __shfl_xor(k0, 16);
            float k0r = k0;
            if (lane < 16)      k0r = k0 * cv - other * sv;
            else if (lane < 32) k0r = other * sv + k0 * cv;
            bf16* kout = Kh + ((size_t)(b * NKV + h) * SEQ + s) * HD;
            kout[lane] = (bf16)k0r; kout[lane + 64] = (bf16)k1;
        }
    } else {
        int idx = bx - 4096;              // vtrans: 512 blocks
        int bh = idx >> 5, st = idx & 31;
        int b = bh >> 3, h = bh & 7;
        __shared__ float tile[64][129];
        int t = threadIdx.x;
        const bf16* src = qkv + ((size_t)(b * SEQ) + st * 64) * NQKV + 5120 + h * HD;
        #pragma unroll
        for (int i = 0; i < 32; ++i) {
            int ii = i * 256 + t;
            int tok = ii >> 7, d = ii & 127;
            tile[tok][d] = (float)src[(size_t)tok * NQKV + d];
        }
        __syncthreads();
        bf16* dst = VT + (size_t)(b * NKV + h) * HD * SEQ + st * 64;
        #pragma unroll
        for (int i = 0; i < 32; ++i) {
            int ii = i * 256 + t;
            int d = ii >> 6, sx = ii & 63;
            dst[(size_t)d * SEQ + sx] = (bf16)tile[sx][d];
        }
    }
}

// ---------------- flash attention, Br=Bc=64, 4 waves x 16 q-rows ----------------
// Q in registers; K/V/P in XOR-swizzled LDS; exp2-domain softmax; qt remapped
// for causal load balance.
__global__ __launch_bounds__(256, 4) void attn_kernel(const bf16* __restrict__ Qh, const bf16* __restrict__ Kh,
                                                      const bf16* __restrict__ VT, const bf16* __restrict__ qkv,
                                                      const int* __restrict__ amask, bf16* __restrict__ attnb) {
    const int bx = blockIdx.x;
    const int hb = bx >> 5;                 // 0..31
    const int head = hb & 15, b = hb >> 4;
    const int qt = ((bx & 31) + hb) & 31;   // co-resident blocks get spread qt
    const int kvh = head >> 1;
    __shared__ __align__(16) bf16 Ks[64 * 128];   // [row][chunk ^ (row&15)]
    __shared__ __align__(16) bf16 Vs[128 * 64];   // [d][chunk ^ (d&7)]
    __shared__ __align__(16) bf16 Ps[4 * 16 * 64];// per-wave, col ^ ((row>>2)*16)
    const int tid = threadIdx.x, wave = tid >> 6, lane = tid & 63;
    const int quad = lane >> 4, cl = lane & 15;

    const bf16* qsrc = Qh + ((size_t)(b * NH + head) * SEQ + qt * 64) * HD;
    bf16x8 aq[4];
    #pragma unroll
    for (int kc = 0; kc < 4; ++kc)
        aq[kc] = *(const bf16x8*)(qsrc + (size_t)(wave * 16 + cl) * HD + kc * 32 + quad * 8);

    float mstate[4], lstate[4];
    f32x4 oacc[8] = {};
    #pragma unroll
    for (int r = 0; r < 4; ++r) { mstate[r] = -1e30f; lstate[r] = 0.0f; }
    const int qrow_glob = qt * 64 + wave * 16 + quad * 4;   // + r
    // exp2-domain: scale = (1/sqrt(128)) * log2(e)
    const float scale = 0.08838834764831845f * 1.4426950408889634f;

    for (int kt = 0; kt <= qt; ++kt) {
        __syncthreads();
        const bf16* ksrc = Kh + ((size_t)(b * NKV + kvh) * SEQ + kt * 64) * HD;
        const bf16* vsrc = VT + (size_t)(b * NKV + kvh) * HD * SEQ + kt * 64;
        #pragma unroll
        for (int j = 0; j < 4; ++j) {
            int s = (j * 4 + wave) * 64 + lane;       // 16B-chunk slot 0..1023
            int rK = s >> 4, cK = s & 15;
            GLOAD_LDS16(ksrc + (size_t)rK * HD + ((cK ^ (rK & 15)) << 3), Ks + (size_t)s * 8);
            int dV = s >> 3, cV = s & 7;
            GLOAD_LDS16(vsrc + (size_t)dV * SEQ + ((cV ^ (dV & 7)) << 3), Vs + (size_t)s * 8);
        }
        __syncthreads();

        f32x4 sc[4] = {};
        #pragma unroll
        for (int nt = 0; nt < 4; ++nt)
            #pragma unroll
            for (int kc = 0; kc < 4; ++kc) {
                bf16x8 bk = *(const bf16x8*)(Ks + (size_t)(nt * 16 + cl) * 128 + (((kc * 4 + quad) ^ cl) << 3));
                sc[nt] = __builtin_amdgcn_mfma_f32_16x16x32_bf16(aq[kc], bk, sc[nt], 0, 0, 0);
            }

        bool colok[4];
        int kcolb[4];
        #pragma unroll
        for (int nt = 0; nt < 4; ++nt) {
            kcolb[nt] = kt * 64 + nt * 16 + cl;
            colok[nt] = (amask[b * SEQ + kcolb[nt]] != 0);
        }
        const bool diag = (kt == qt);

        float alpha[4];
        #pragma unroll
        for (int r = 0; r < 4; ++r) {
            float rv[4];
            float tmax = -1e30f;
            #pragma unroll
            for (int nt = 0; nt < 4; ++nt) {
                float v = sc[nt][r] * scale;
                bool ok = colok[nt] && (!diag || (kcolb[nt] <= qrow_glob + r));
                v = ok ? v : -1e30f;
                rv[nt] = v;
                tmax = fmaxf(tmax, v);
            }
            #pragma unroll
            for (int off = 8; off; off >>= 1) tmax = fmaxf(tmax, __shfl_xor(tmax, off));
            float mnew = fmaxf(mstate[r], tmax);
            float al = exp2f(mstate[r] - mnew);
            mstate[r] = mnew; alpha[r] = al;
            float rsum = 0.0f;
            int prow = quad * 4 + r;
            #pragma unroll
            for (int nt = 0; nt < 4; ++nt) {
                float p = exp2f(rv[nt] - mnew);
                rsum += p;
                Ps[wave * 1024 + prow * 64 + ((nt * 16 + cl) ^ (quad << 4))] = (bf16)p;
            }
            #pragma unroll
            for (int off = 8; off; off >>= 1) rsum += __shfl_xor(rsum, off);
            lstate[r] = lstate[r] * al + rsum;
        }
        #pragma unroll
        for (int n2 = 0; n2 < 8; ++n2)
            #pragma unroll
            for (int r = 0; r < 4; ++r) oacc[n2][r] *= alpha[r];

        bf16x8 ap[2];
        #pragma unroll
        for (int c = 0; c < 2; ++c)
            ap[c] = *(const bf16x8*)(Ps + wave * 1024 + cl * 64 + ((c * 32 + quad * 8) ^ ((cl >> 2) << 4)));
        #pragma unroll
        for (int n2 = 0; n2 < 8; ++n2)
            #pragma unroll
            for (int c = 0; c < 2; ++c) {
                bf16x8 bv = *(const bf16x8*)(Vs + (size_t)(n2 * 16 + cl) * 64 + (((c * 4 + quad) ^ (cl & 7)) << 3));
                oacc[n2] = __builtin_amdgcn_mfma_f32_16x16x32_bf16(ap[c], bv, oacc[n2], 0, 0, 0);
            }
    }

    #pragma unroll
    for (int r = 0; r < 4; ++r) {
        int srow = qt * 64 + wave * 16 + quad * 4 + r;
        float linv = 1.0f / lstate[r];
        #pragma unroll
        for (int n2 = 0; n2 < 8; ++n2) {
            int d = n2 * 16 + cl;
            float g = (float)qkv[(size_t)(b * SEQ + srow) * NQKV + head * 256 + 128 + d];
            float sig = 1.0f / (1.0f + __expf(-g));
            float v = oacc[n2][r] * linv * sig;
            attnb[(size_t)(b * SEQ + srow) * HID + head * HD + d] = (bf16)v;
        }
    }
}

// ---------------- launch ----------------
extern "C" void kernel_launch(void* const* d_in, const int* in_sizes, int n_in,
                              void* d_out, int out_size, void* d_ws, size_t ws_size,
                              hipStream_t stream) {
    const float* x        = (const float*)d_in[0];
    const int*   amask    = (const int*)d_in[1];
    const int*   positions= (const int*)d_in[2];
    const float* Wq       = (const float*)d_in[3];
    const float* Wk       = (const float*)d_in[4];
    const float* Wv       = (const float*)d_in[5];
    const float* Wo       = (const float*)d_in[6];
    const float* qnw      = (const float*)d_in[7];
    const float* knw      = (const float*)d_in[8];
    float* out = (float*)d_out;
    char* ws = (char*)d_ws;

    bf16* xb    = (bf16*)(ws);                         // 16,777,216 B
    bf16* wqkvT = (bf16*)(ws + 16777216);              // 25,165,824 B
    bf16* woT   = (bf16*)(ws + 41943040);              //  8,388,608 B
    bf16* qkv   = (bf16*)(ws + 50331648);              // 50,331,648 B
    bf16* Qh    = (bf16*)(ws + 100663296);             // 16,777,216 B
    bf16* Kh    = (bf16*)(ws + 117440512);             //  8,388,608 B
    bf16* VT    = (bf16*)(ws + 125829120);             //  8,388,608 B
    bf16* attnb = (bf16*)(ws + 134217728);             // 16,777,216 B -> 150,994,944 total

    prep_kernel<<<12288, 256, 0, stream>>>(x, xb, Wq, Wk, Wv, Wo, wqkvT, woT);
    gemm_bt<true><<<dim3(48, 32), 256, 0, stream>>>(xb, wqkvT, qkv, MTOT, NQKV, HID);
    post_kernel<<<4608, 256, 0, stream>>>(qkv, qnw, knw, positions, Qh, Kh, VT);
    attn_kernel<<<1024, 256, 0, stream>>>(Qh, Kh, VT, qkv, amask, attnb);
    gemm_bt<false><<<dim3(16, 32), 256, 0, stream>>>(attnb, woT, out, MTOT, HID, HID);

    (void)in_sizes; (void)n_in; (void)out_size; (void)ws_size;
}